// Round 1
// baseline (556.458 us; speedup 1.0000x reference)
//
#include <hip/hip_runtime.h>
#include <hip/hip_bf16.h>

// TuckER: out[b] = sum_{i,j,k} p[b,i] r[b,j] q[b,k] W[i,j,k]
// Strategy: WR[r,i,k] = sum_j R[r,j] W[i,j,k] for all 1000 r rows (33.5 GFLOP),
// then out[b] = p_b^T WR[rs_b] q_b (memory-bound, WR bf16 fits L3).

#define DDIM 256
#define S1_TR 128
#define S1_TK 128
#define S1_KS 8

typedef unsigned int uint;

// ---------------- Stage 1: WR[r,i,k] = sum_j R[r,j]*W[i,j,k], bf16 out ------
__global__ __launch_bounds__(256)
void stage1_kernel(const float* __restrict__ R, const float* __restrict__ W,
                   __hip_bfloat16* __restrict__ WRc, int r_lo, int r_cnt) {
    const int i  = blockIdx.z;
    const int r0 = blockIdx.x * S1_TR;   // chunk-relative r tile base
    const int k0 = blockIdx.y * S1_TK;
    const int t  = threadIdx.x;

    __shared__ float Rt[S1_KS][S1_TR + 4];   // [j][r]
    __shared__ float Wt[S1_KS][S1_TK + 4];   // [j][k]

    const int tr = (t >> 4) * 8;   // this thread's 8 r rows
    const int tk = (t & 15) * 8;   // this thread's 8 k cols

    float acc[8][8];
#pragma unroll
    for (int a = 0; a < 8; ++a)
#pragma unroll
        for (int c = 0; c < 8; ++c) acc[a][c] = 0.f;

    const int rt_r  = t >> 1;        // 0..127
    const int rt_j4 = (t & 1) * 4;   // 0 or 4
    const int wt_j  = t >> 5;        // 0..7
    const int wt_k4 = (t & 31) * 4;  // 0..124

    const float* Wi = W + (size_t)i * (DDIM * DDIM);

    for (int j0 = 0; j0 < DDIM; j0 += S1_KS) {
        // fetch next tiles to registers
        float4 rv = make_float4(0.f, 0.f, 0.f, 0.f);
        int rr = r0 + rt_r;
        if (rr < r_cnt)
            rv = *reinterpret_cast<const float4*>(
                R + (size_t)(r_lo + rr) * DDIM + j0 + rt_j4);
        float4 wv = *reinterpret_cast<const float4*>(
            Wi + (size_t)(j0 + wt_j) * DDIM + k0 + wt_k4);

        __syncthreads();  // previous tile fully consumed
        Rt[rt_j4 + 0][rt_r] = rv.x;
        Rt[rt_j4 + 1][rt_r] = rv.y;
        Rt[rt_j4 + 2][rt_r] = rv.z;
        Rt[rt_j4 + 3][rt_r] = rv.w;
        *reinterpret_cast<float4*>(&Wt[wt_j][wt_k4]) = wv;
        __syncthreads();

#pragma unroll
        for (int jj = 0; jj < S1_KS; ++jj) {
            float4 ra = *reinterpret_cast<const float4*>(&Rt[jj][tr]);
            float4 rb = *reinterpret_cast<const float4*>(&Rt[jj][tr + 4]);
            float4 wa = *reinterpret_cast<const float4*>(&Wt[jj][tk]);
            float4 wb = *reinterpret_cast<const float4*>(&Wt[jj][tk + 4]);
            float rv8[8] = {ra.x, ra.y, ra.z, ra.w, rb.x, rb.y, rb.z, rb.w};
            float wv8[8] = {wa.x, wa.y, wa.z, wa.w, wb.x, wb.y, wb.z, wb.w};
#pragma unroll
            for (int a = 0; a < 8; ++a)
#pragma unroll
                for (int c = 0; c < 8; ++c)
                    acc[a][c] += rv8[a] * wv8[c];
        }
    }

    // store 8x8 bf16
#pragma unroll
    for (int a = 0; a < 8; ++a) {
        int rr = r0 + tr + a;
        if (rr < r_cnt) {
            union { unsigned short u16[8]; uint4 v; } cvt;
#pragma unroll
            for (int c = 0; c < 8; ++c) {
                __hip_bfloat16 h = __float2bfloat16(acc[a][c]);
                cvt.u16[c] = *reinterpret_cast<unsigned short*>(&h);
            }
            *reinterpret_cast<uint4*>(
                WRc + ((size_t)rr * DDIM + i) * DDIM + k0 + tk) = cvt.v;
        }
    }
}

// ---------------- Stage 2: out[b] = p_b^T WR[rs_b] q_b ----------------------
__global__ __launch_bounds__(256)
void stage2_kernel(const int* __restrict__ rs, const int* __restrict__ ps,
                   const int* __restrict__ qs, const float* __restrict__ P,
                   const float* __restrict__ Q,
                   const __hip_bfloat16* __restrict__ WRc,
                   float* __restrict__ out, int r_lo, int r_hi) {
    const int b = blockIdx.x;
    const int r = rs[b];
    if (r < r_lo || r >= r_hi) return;  // handled by another chunk

    __shared__ float p_s[DDIM];
    __shared__ float q_s[DDIM];
    const int t = threadIdx.x;
    p_s[t] = P[(size_t)ps[b] * DDIM + t];
    q_s[t] = Q[(size_t)qs[b] * DDIM + t];
    __syncthreads();

    const int ti = t >> 5;        // 0..7  (i offset)
    const int tk = (t & 31) * 8;  // k base, 8 bf16 per thread

    float qv[8];
#pragma unroll
    for (int j = 0; j < 8; ++j) qv[j] = q_s[tk + j];

    const __hip_bfloat16* base =
        WRc + (size_t)(r - r_lo) * (DDIM * DDIM);

    float acc = 0.f;
    for (int i = ti; i < DDIM; i += 8) {
        float pi = p_s[i];
        uint4 v = *reinterpret_cast<const uint4*>(base + (size_t)i * DDIM + tk);
        const unsigned short* h = reinterpret_cast<const unsigned short*>(&v);
        float dot = 0.f;
#pragma unroll
        for (int j = 0; j < 8; ++j) {
            float w = __uint_as_float(((uint)h[j]) << 16);
            dot += w * qv[j];
        }
        acc += pi * dot;
    }

    // block reduce (4 waves)
#pragma unroll
    for (int off = 32; off; off >>= 1) acc += __shfl_down(acc, off, 64);
    __shared__ float red[4];
    if ((t & 63) == 0) red[t >> 6] = acc;
    __syncthreads();
    if (t == 0) out[b] = red[0] + red[1] + red[2] + red[3];
}

// ---------------- Norms -----------------------------------------------------
__global__ void zero_norms(float* n) {
    if (threadIdx.x < 3) n[threadIdx.x] = 0.f;
}

__global__ __launch_bounds__(256)
void norm_kernel(const int* __restrict__ idx, const float* __restrict__ table,
                 float* __restrict__ accum, int nB) {
    float acc = 0.f;
    const size_t total = (size_t)nB * DDIM;
    for (size_t e = (size_t)blockIdx.x * 256 + threadIdx.x; e < total;
         e += (size_t)gridDim.x * 256) {
        int b = (int)(e >> 8);
        int d = (int)(e & 255);
        float v = table[(size_t)idx[b] * DDIM + d];
        acc += v * v;
    }
#pragma unroll
    for (int off = 32; off; off >>= 1) acc += __shfl_down(acc, off, 64);
    __shared__ float red[4];
    if ((threadIdx.x & 63) == 0) red[threadIdx.x >> 6] = acc;
    __syncthreads();
    if (threadIdx.x == 0) atomicAdd(accum, red[0] + red[1] + red[2] + red[3]);
}

__global__ void finalize_kernel(const float* __restrict__ n,
                                float* __restrict__ out, int nB) {
    if (threadIdx.x == 0 && blockIdx.x == 0)
        out[nB] = 0.01f * (sqrtf(n[0]) + sqrtf(n[1]) + sqrtf(n[2]));
}

// ---------------- Launch -----------------------------------------------------
extern "C" void kernel_launch(void* const* d_in, const int* in_sizes, int n_in,
                              void* d_out, int out_size, void* d_ws,
                              size_t ws_size, hipStream_t stream) {
    const int*   ps = (const int*)d_in[0];
    const int*   qs = (const int*)d_in[1];
    const int*   rs = (const int*)d_in[2];
    const float* P  = (const float*)d_in[3];
    const float* Q  = (const float*)d_in[4];
    const float* R  = (const float*)d_in[5];
    const float* W  = (const float*)d_in[6];
    float* out = (float*)d_out;

    const int B      = in_sizes[0];
    const int NUM_RS = in_sizes[5] / DDIM;

    // ws layout: [0,256) norm accumulators; [256, ...) WR bf16 chunk
    float* norms = (float*)d_ws;
    __hip_bfloat16* WR = (__hip_bfloat16*)((char*)d_ws + 256);
    size_t ws_for_wr = (ws_size > 256) ? ws_size - 256 : 0;
    int max_chunk = (int)(ws_for_wr / ((size_t)DDIM * DDIM * 2));
    if (max_chunk > NUM_RS) max_chunk = NUM_RS;
    if (max_chunk < 1) max_chunk = 1;

    // regularizer
    zero_norms<<<1, 64, 0, stream>>>(norms);
    norm_kernel<<<2048, 256, 0, stream>>>(ps, P, norms + 0, B);
    norm_kernel<<<2048, 256, 0, stream>>>(qs, Q, norms + 1, B);
    norm_kernel<<<2048, 256, 0, stream>>>(rs, R, norms + 2, B);
    finalize_kernel<<<1, 64, 0, stream>>>(norms, out, B);

    for (int lo = 0; lo < NUM_RS; lo += max_chunk) {
        int cnt = NUM_RS - lo;
        if (cnt > max_chunk) cnt = max_chunk;
        dim3 g1((cnt + S1_TR - 1) / S1_TR, DDIM / S1_TK, DDIM);
        stage1_kernel<<<g1, 256, 0, stream>>>(R, W, WR, lo, cnt);
        stage2_kernel<<<B, 256, 0, stream>>>(rs, ps, qs, P, Q, WR, out, lo,
                                             lo + cnt);
    }
}

// Round 2
// 359.014 us; speedup vs baseline: 1.5500x; 1.5500x over previous
//
#include <hip/hip_runtime.h>
#include <hip/hip_bf16.h>

// TuckER: out[b] = sum_{i,j,k} p[b,i] r[b,j] q[b,k] W[i,j,k]
// Pipeline:
//   conv_r:   R fp32 -> bf16                      (0.5 MB)
//   conv_wt:  W[i][j][k] fp32 -> Wt[(i,k)][j] bf16 (transpose, 33.5 MB out)
//   stage1:   WR[r,(i,k)] = sum_j R[r,j] Wt[(i,k),j]   MFMA bf16 GEMM
//             M=1000 N=65536 K=256  (33.5 GFLOP)
//   stage2:   out[b] = p_b^T WR[rs_b] q_b, bucketed by r (WR read ~1x)
//   norms:    REG*(||p||+||q||+||r||)

#define DDIM 256
#define NIK  65536   // DDIM*DDIM
#define BM   128     // r rows per block (stage1)
#define BN   128     // ik cols per block
#define BK   64      // j per k-iter

typedef unsigned int uint;
typedef __attribute__((ext_vector_type(8))) short bf16x8;
typedef __attribute__((ext_vector_type(4))) float f32x4;

static __device__ __forceinline__ unsigned short f2bf(float f) {
    __hip_bfloat16 h = __float2bfloat16(f);
    return *reinterpret_cast<unsigned short*>(&h);
}
static __device__ __forceinline__ float bf2f(unsigned short u) {
    return __uint_as_float(((uint)u) << 16);
}

#define GLOAD_LDS16(gsrc, ldst)                                                \
    __builtin_amdgcn_global_load_lds(                                          \
        (const __attribute__((address_space(1))) void*)(gsrc),                 \
        (__attribute__((address_space(3))) void*)(ldst), 16, 0, 0)

// ---------------- convert R to bf16 -----------------------------------------
__global__ __launch_bounds__(256)
void conv_r_kernel(const float* __restrict__ R, unsigned short* __restrict__ Rb,
                   int n4) {
    int idx = blockIdx.x * 256 + threadIdx.x;
    if (idx < n4) {
        float4 v = *reinterpret_cast<const float4*>(R + idx * 4);
        ushort4 o;
        o.x = f2bf(v.x); o.y = f2bf(v.y); o.z = f2bf(v.z); o.w = f2bf(v.w);
        *reinterpret_cast<ushort4*>(Rb + idx * 4) = o;
    }
}

// ---------------- transpose-convert W: [i][j][k] f32 -> [(i,k)][j] bf16 -----
__global__ __launch_bounds__(256)
void conv_wt_kernel(const float* __restrict__ W, unsigned short* __restrict__ Wt) {
    const int k0 = blockIdx.x * 64;   // 4 tiles
    const int j0 = blockIdx.y * 128;  // 2 tiles
    const int i  = blockIdx.z;
    const int t  = threadIdx.x;

    __shared__ float sT[64][129];  // [k][j], pad 129 (4-way max conflict)

    const float* Wi = W + (size_t)i * NIK;
#pragma unroll
    for (int it = 0; it < 8; ++it) {
        int slot = it * 256 + t;
        int jj = slot >> 4, c = slot & 15;
        float4 v = *reinterpret_cast<const float4*>(
            Wi + (size_t)(j0 + jj) * DDIM + k0 + c * 4);
        sT[c * 4 + 0][jj] = v.x;
        sT[c * 4 + 1][jj] = v.y;
        sT[c * 4 + 2][jj] = v.z;
        sT[c * 4 + 3][jj] = v.w;
    }
    __syncthreads();
#pragma unroll
    for (int it = 0; it < 4; ++it) {
        int u = it * 256 + t;
        int kk = u >> 4, jg = u & 15;
        union { unsigned short us[8]; uint4 v; } pk;
#pragma unroll
        for (int m = 0; m < 8; ++m) pk.us[m] = f2bf(sT[kk][jg * 8 + m]);
        *reinterpret_cast<uint4*>(
            Wt + (size_t)(i * DDIM + k0 + kk) * DDIM + j0 + jg * 8) = pk.v;
    }
}

// ---------------- Stage 1: MFMA GEMM ----------------------------------------
// A op = Wt tile (ik-rows x j), B op = R tile (r-cols x j) -> D[ik][r]
__global__ __launch_bounds__(256)
void stage1_kernel(const unsigned short* __restrict__ Rb,
                   const unsigned short* __restrict__ Wt,
                   unsigned short* __restrict__ WR,
                   int r_lo, int cnt) {
    const int t    = threadIdx.x;
    const int lane = t & 63;
    const int wid  = t >> 6;
    const int r0   = blockIdx.x * BM;  // chunk-relative r base
    const int n0   = blockIdx.y * BN;  // ik base

    __shared__ char smem[2 * BM * BK * 2];  // 16KB A(R) + 16KB B(Wt)
    char* Alds = smem;                 // [128 r][64 j] bf16, XOR-swizzled
    char* Blds = smem + BM * BK * 2;   // [128 ik][64 j]

    const int wr = (wid >> 1) * 64;  // wave r offset in tile
    const int wn = (wid & 1) * 64;   // wave ik offset in tile

    f32x4 acc[4][4];
#pragma unroll
    for (int a = 0; a < 4; ++a)
#pragma unroll
        for (int b = 0; b < 4; ++b) {
            acc[a][b][0] = 0.f; acc[a][b][1] = 0.f;
            acc[a][b][2] = 0.f; acc[a][b][3] = 0.f;
        }

    for (int kt = 0; kt < 4; ++kt) {
        const int j0 = kt * BK;
        __syncthreads();  // prev iter's fragment reads complete
#pragma unroll
        for (int c = 0; c < 4; ++c) {  // A tile: R rows (clamped)
            int u = c * 256 + t;
            int row = u >> 3, g = u & 7;
            int rg = r0 + row;
            if (rg >= cnt) rg = 0;  // clamped rows masked at store
            const unsigned short* src =
                Rb + (size_t)(r_lo + rg) * DDIM + j0 + ((g ^ (row & 7)) << 3);
            GLOAD_LDS16(src, Alds + u * 16);
        }
#pragma unroll
        for (int c = 0; c < 4; ++c) {  // B tile: Wt rows
            int u = c * 256 + t;
            int row = u >> 3, g = u & 7;
            const unsigned short* src =
                Wt + (size_t)(n0 + row) * DDIM + j0 + ((g ^ (row & 7)) << 3);
            GLOAD_LDS16(src, Blds + u * 16);
        }
        __syncthreads();  // drains vmcnt: staged data visible

#pragma unroll
        for (int ks = 0; ks < 2; ++ks) {
            bf16x8 a[4], b[4];
            const int jg = ks * 4 + (lane >> 4);
#pragma unroll
            for (int f = 0; f < 4; ++f) {
                int rowB = wn + f * 16 + (lane & 15);
                a[f] = *reinterpret_cast<const bf16x8*>(
                    Blds + rowB * 128 + ((jg ^ (rowB & 7)) << 4));
                int rowA = wr + f * 16 + (lane & 15);
                b[f] = *reinterpret_cast<const bf16x8*>(
                    Alds + rowA * 128 + ((jg ^ (rowA & 7)) << 4));
            }
#pragma unroll
            for (int fi = 0; fi < 4; ++fi)
#pragma unroll
                for (int fr = 0; fr < 4; ++fr)
                    acc[fi][fr] = __builtin_amdgcn_mfma_f32_16x16x32_bf16(
                        a[fi], b[fr], acc[fi][fr], 0, 0, 0);
        }
    }

    // store: D row = ik = (lane>>4)*4+v (contiguous) ; D col = r = lane&15
    const int rbase  = r0 + wr + (lane & 15);
    const int ikbase = n0 + wn + ((lane >> 4) << 2);
#pragma unroll
    for (int fr = 0; fr < 4; ++fr) {
        int r = rbase + fr * 16;
        if (r < cnt) {
#pragma unroll
            for (int fi = 0; fi < 4; ++fi) {
                union { unsigned short us[4]; uint2 v; } pk;
#pragma unroll
                for (int v = 0; v < 4; ++v) pk.us[v] = f2bf(acc[fi][fr][v]);
                *reinterpret_cast<uint2*>(
                    WR + (size_t)r * NIK + ikbase + fi * 16) = pk.v;
            }
        }
    }
}

// ---------------- Stage 2: bucketed bilinear forms --------------------------
__global__ __launch_bounds__(256)
void stage2_kernel(const int* __restrict__ rs, const int* __restrict__ ps,
                   const int* __restrict__ qs, const float* __restrict__ P,
                   const float* __restrict__ Q,
                   const unsigned short* __restrict__ WR,
                   float* __restrict__ out, int r_lo, int B) {
    const int r_rel = blockIdx.x;
    const int r     = r_lo + r_rel;
    const int t     = threadIdx.x;

    __shared__ int   list[256];
    __shared__ int   nm;
    __shared__ float Lp[8][DDIM];
    __shared__ float Lq[8][DDIM];
    __shared__ float red[8][4];

    const unsigned short* M = WR + (size_t)r_rel * NIK;
    const int g = t >> 6;   // wave id -> i-subrow
    const int c = t & 63;   // k-group (4 elems)

    for (int base = 0; base < B; base += 256) {
        if (t == 0) nm = 0;
        __syncthreads();
        int b = base + t;
        if (b < B && rs[b] == r) {
            int slot = atomicAdd(&nm, 1);
            list[slot] = b;
        }
        __syncthreads();
        const int total = nm;
        for (int s0 = 0; s0 < total; s0 += 8) {
            const int ns = min(8, total - s0);
            for (int x = t; x < ns * DDIM; x += 256) {
                int s = x >> 8, d = x & 255;
                int bb = list[s0 + s];
                Lp[s][d] = P[(size_t)ps[bb] * DDIM + d];
                Lq[s][d] = Q[(size_t)qs[bb] * DDIM + d];
            }
            __syncthreads();

            float qq[8][4];
            float acc[8];
#pragma unroll
            for (int s = 0; s < 8; ++s) {
                acc[s] = 0.f;
                if (s < ns) {
#pragma unroll
                    for (int m = 0; m < 4; ++m) qq[s][m] = Lq[s][c * 4 + m];
                }
            }
            for (int i0 = 0; i0 < DDIM; i0 += 4) {
                int i = i0 + g;
                uint2 v = *reinterpret_cast<const uint2*>(M + (size_t)i * DDIM + c * 4);
                const unsigned short* h = reinterpret_cast<const unsigned short*>(&v);
                float m0 = bf2f(h[0]), m1 = bf2f(h[1]);
                float m2 = bf2f(h[2]), m3 = bf2f(h[3]);
#pragma unroll
                for (int s = 0; s < 8; ++s)
                    if (s < ns) {
                        float pv = Lp[s][i];
                        acc[s] += pv * (m0 * qq[s][0] + m1 * qq[s][1] +
                                        m2 * qq[s][2] + m3 * qq[s][3]);
                    }
            }
#pragma unroll
            for (int s = 0; s < 8; ++s)
                if (s < ns) {
                    float a = acc[s];
#pragma unroll
                    for (int off = 32; off; off >>= 1) a += __shfl_down(a, off, 64);
                    if (c == 0) red[s][g] = a;
                }
            __syncthreads();
            if (t < ns) out[list[s0 + t]] = red[t][0] + red[t][1] + red[t][2] + red[t][3];
            __syncthreads();
        }
        __syncthreads();
    }
}

// ---------------- Norms -----------------------------------------------------
__global__ void zero_norms(float* n) {
    if (threadIdx.x < 3) n[threadIdx.x] = 0.f;
}

__global__ __launch_bounds__(256)
void norm_kernel(const int* __restrict__ ps, const int* __restrict__ qs,
                 const int* __restrict__ rs, const float* __restrict__ P,
                 const float* __restrict__ Q, const float* __restrict__ R,
                 float* __restrict__ accum, int B) {
    const int which = blockIdx.y;
    const int*   idx = (which == 0) ? ps : (which == 1) ? qs : rs;
    const float* tab = (which == 0) ? P : (which == 1) ? Q : R;
    float a = 0.f;
    const int total = B * 64;  // float4 slots
    for (int e = blockIdx.x * 256 + threadIdx.x; e < total; e += gridDim.x * 256) {
        int b = e >> 6, cc = e & 63;
        float4 v = *reinterpret_cast<const float4*>(tab + (size_t)idx[b] * DDIM + cc * 4);
        a += v.x * v.x + v.y * v.y + v.z * v.z + v.w * v.w;
    }
#pragma unroll
    for (int off = 32; off; off >>= 1) a += __shfl_down(a, off, 64);
    __shared__ float red[4];
    if ((threadIdx.x & 63) == 0) red[threadIdx.x >> 6] = a;
    __syncthreads();
    if (threadIdx.x == 0) atomicAdd(accum + which, red[0] + red[1] + red[2] + red[3]);
}

__global__ void finalize_kernel(const float* __restrict__ n,
                                float* __restrict__ out, int nB) {
    if (threadIdx.x == 0 && blockIdx.x == 0)
        out[nB] = 0.01f * (sqrtf(n[0]) + sqrtf(n[1]) + sqrtf(n[2]));
}

// ---------------- Launch -----------------------------------------------------
extern "C" void kernel_launch(void* const* d_in, const int* in_sizes, int n_in,
                              void* d_out, int out_size, void* d_ws,
                              size_t ws_size, hipStream_t stream) {
    const int*   ps = (const int*)d_in[0];
    const int*   qs = (const int*)d_in[1];
    const int*   rs = (const int*)d_in[2];
    const float* P  = (const float*)d_in[3];
    const float* Q  = (const float*)d_in[4];
    const float* R  = (const float*)d_in[5];
    const float* W  = (const float*)d_in[6];
    float* out = (float*)d_out;

    const int B      = in_sizes[0];
    const int NUM_RS = in_sizes[5] / DDIM;

    // ws layout
    size_t off_norm = 0;                                  // 3 f32 (256 B slot)
    size_t off_r    = 256;                                // Rb: NUM_RS*256*2
    size_t off_wt   = off_r + (size_t)NUM_RS * DDIM * 2;  // Wt: 33.5 MB
    off_wt = (off_wt + 255) & ~(size_t)255;
    size_t off_wr   = off_wt + (size_t)NIK * DDIM * 2;
    off_wr = (off_wr + 255) & ~(size_t)255;

    float*          norms = (float*)((char*)d_ws + off_norm);
    unsigned short* Rb    = (unsigned short*)((char*)d_ws + off_r);
    unsigned short* Wt    = (unsigned short*)((char*)d_ws + off_wt);
    unsigned short* WR    = (unsigned short*)((char*)d_ws + off_wr);

    size_t wr_bytes = (ws_size > off_wr) ? ws_size - off_wr : 0;
    int max_chunk = (int)(wr_bytes / ((size_t)NIK * 2));
    if (max_chunk > NUM_RS) max_chunk = NUM_RS;
    if (max_chunk < 1) max_chunk = 1;

    // regularizer
    zero_norms<<<1, 64, 0, stream>>>(norms);
    norm_kernel<<<dim3(128, 3), 256, 0, stream>>>(ps, qs, rs, P, Q, R, norms, B);
    finalize_kernel<<<1, 64, 0, stream>>>(norms, out, B);

    // conversions
    conv_r_kernel<<<(NUM_RS * DDIM / 4 + 255) / 256, 256, 0, stream>>>(
        R, Rb, NUM_RS * DDIM / 4);
    conv_wt_kernel<<<dim3(4, 2, DDIM), 256, 0, stream>>>(W, Wt);

    for (int lo = 0; lo < NUM_RS; lo += max_chunk) {
        int cnt = NUM_RS - lo;
        if (cnt > max_chunk) cnt = max_chunk;
        dim3 g1((cnt + BM - 1) / BM, NIK / BN);
        stage1_kernel<<<g1, 256, 0, stream>>>(Rb, Wt, WR, lo, cnt);
        stage2_kernel<<<cnt, 256, 0, stream>>>(rs, ps, qs, P, Q, WR, out, lo, B);
    }
}

// Round 3
// 192.931 us; speedup vs baseline: 2.8842x; 1.8608x over previous
//
#include <hip/hip_runtime.h>
#include <hip/hip_bf16.h>

// TuckER: out[b] = sum_{i,j,k} p[b,i] r[b,j] q[b,k] W[i,j,k]
// Pipeline:
//   conv_r:   R fp32 -> bf16
//   conv_wt:  W[i][j][k] fp32 -> Wt[(i,k)][j] bf16 (transpose)
//   stage1:   WR[r,(i,k)] = sum_j R[r,j] Wt[(i,k),j]   MFMA bf16 GEMM
//   CSR:      bucket samples by r (hist/scan/fill)
//   stage2:   partial[ic,b] = p_b[ic-chunk]^T WR[rs_b][chunk] q_b  (grid 1000x4)
//   sum_out:  out[b] = sum_ic partial[ic,b]
//   norms:    REG*(||p||+||q||+||r||)

#define DDIM 256
#define NIK  65536   // DDIM*DDIM
#define BM   128     // r rows per block (stage1)
#define BN   128     // ik cols per block
#define BK   64      // j per k-iter
#define NCH  4       // stage2 i-chunks

typedef unsigned int uint;
typedef __attribute__((ext_vector_type(8))) short bf16x8;
typedef __attribute__((ext_vector_type(4))) float f32x4;

static __device__ __forceinline__ unsigned short f2bf(float f) {
    __hip_bfloat16 h = __float2bfloat16(f);
    return *reinterpret_cast<unsigned short*>(&h);
}
static __device__ __forceinline__ float bf2f(unsigned short u) {
    return __uint_as_float(((uint)u) << 16);
}

#define GLOAD_LDS16(gsrc, ldst)                                                \
    __builtin_amdgcn_global_load_lds(                                          \
        (const __attribute__((address_space(1))) void*)(gsrc),                 \
        (__attribute__((address_space(3))) void*)(ldst), 16, 0, 0)

// ---------------- convert R to bf16 -----------------------------------------
__global__ __launch_bounds__(256)
void conv_r_kernel(const float* __restrict__ R, unsigned short* __restrict__ Rb,
                   int n4) {
    int idx = blockIdx.x * 256 + threadIdx.x;
    if (idx < n4) {
        float4 v = *reinterpret_cast<const float4*>(R + idx * 4);
        ushort4 o;
        o.x = f2bf(v.x); o.y = f2bf(v.y); o.z = f2bf(v.z); o.w = f2bf(v.w);
        *reinterpret_cast<ushort4*>(Rb + idx * 4) = o;
    }
}

// ---------------- transpose-convert W: [i][j][k] f32 -> [(i,k)][j] bf16 -----
__global__ __launch_bounds__(256)
void conv_wt_kernel(const float* __restrict__ W, unsigned short* __restrict__ Wt) {
    const int k0 = blockIdx.x * 64;
    const int j0 = blockIdx.y * 128;
    const int i  = blockIdx.z;
    const int t  = threadIdx.x;

    __shared__ float sT[64][129];

    const float* Wi = W + (size_t)i * NIK;
#pragma unroll
    for (int it = 0; it < 8; ++it) {
        int slot = it * 256 + t;
        int jj = slot >> 4, c = slot & 15;
        float4 v = *reinterpret_cast<const float4*>(
            Wi + (size_t)(j0 + jj) * DDIM + k0 + c * 4);
        sT[c * 4 + 0][jj] = v.x;
        sT[c * 4 + 1][jj] = v.y;
        sT[c * 4 + 2][jj] = v.z;
        sT[c * 4 + 3][jj] = v.w;
    }
    __syncthreads();
#pragma unroll
    for (int it = 0; it < 4; ++it) {
        int u = it * 256 + t;
        int kk = u >> 4, jg = u & 15;
        union { unsigned short us[8]; uint4 v; } pk;
#pragma unroll
        for (int m = 0; m < 8; ++m) pk.us[m] = f2bf(sT[kk][jg * 8 + m]);
        *reinterpret_cast<uint4*>(
            Wt + (size_t)(i * DDIM + k0 + kk) * DDIM + j0 + jg * 8) = pk.v;
    }
}

// ---------------- Stage 1: MFMA GEMM ----------------------------------------
__global__ __launch_bounds__(256)
void stage1_kernel(const unsigned short* __restrict__ Rb,
                   const unsigned short* __restrict__ Wt,
                   unsigned short* __restrict__ WR,
                   int r_lo, int cnt) {
    const int t    = threadIdx.x;
    const int lane = t & 63;
    const int wid  = t >> 6;
    const int r0   = blockIdx.x * BM;
    const int n0   = blockIdx.y * BN;

    __shared__ char smem[2 * BM * BK * 2];
    char* Alds = smem;
    char* Blds = smem + BM * BK * 2;

    const int wr = (wid >> 1) * 64;
    const int wn = (wid & 1) * 64;

    f32x4 acc[4][4];
#pragma unroll
    for (int a = 0; a < 4; ++a)
#pragma unroll
        for (int b = 0; b < 4; ++b) {
            acc[a][b][0] = 0.f; acc[a][b][1] = 0.f;
            acc[a][b][2] = 0.f; acc[a][b][3] = 0.f;
        }

    for (int kt = 0; kt < 4; ++kt) {
        const int j0 = kt * BK;
        __syncthreads();
#pragma unroll
        for (int c = 0; c < 4; ++c) {
            int u = c * 256 + t;
            int row = u >> 3, g = u & 7;
            int rg = r0 + row;
            if (rg >= cnt) rg = 0;
            const unsigned short* src =
                Rb + (size_t)(r_lo + rg) * DDIM + j0 + ((g ^ (row & 7)) << 3);
            GLOAD_LDS16(src, Alds + u * 16);
        }
#pragma unroll
        for (int c = 0; c < 4; ++c) {
            int u = c * 256 + t;
            int row = u >> 3, g = u & 7;
            const unsigned short* src =
                Wt + (size_t)(n0 + row) * DDIM + j0 + ((g ^ (row & 7)) << 3);
            GLOAD_LDS16(src, Blds + u * 16);
        }
        __syncthreads();

#pragma unroll
        for (int ks = 0; ks < 2; ++ks) {
            bf16x8 a[4], b[4];
            const int jg = ks * 4 + (lane >> 4);
#pragma unroll
            for (int f = 0; f < 4; ++f) {
                int rowB = wn + f * 16 + (lane & 15);
                a[f] = *reinterpret_cast<const bf16x8*>(
                    Blds + rowB * 128 + ((jg ^ (rowB & 7)) << 4));
                int rowA = wr + f * 16 + (lane & 15);
                b[f] = *reinterpret_cast<const bf16x8*>(
                    Alds + rowA * 128 + ((jg ^ (rowA & 7)) << 4));
            }
#pragma unroll
            for (int fi = 0; fi < 4; ++fi)
#pragma unroll
                for (int fr = 0; fr < 4; ++fr)
                    acc[fi][fr] = __builtin_amdgcn_mfma_f32_16x16x32_bf16(
                        a[fi], b[fr], acc[fi][fr], 0, 0, 0);
        }
    }

    const int rbase  = r0 + wr + (lane & 15);
    const int ikbase = n0 + wn + ((lane >> 4) << 2);
#pragma unroll
    for (int fr = 0; fr < 4; ++fr) {
        int r = rbase + fr * 16;
        if (r < cnt) {
#pragma unroll
            for (int fi = 0; fi < 4; ++fi) {
                union { unsigned short us[4]; uint2 v; } pk;
#pragma unroll
                for (int v = 0; v < 4; ++v) pk.us[v] = f2bf(acc[fi][fr][v]);
                *reinterpret_cast<uint2*>(
                    WR + (size_t)r * NIK + ikbase + fi * 16) = pk.v;
            }
        }
    }
}

// ---------------- CSR bucketing ---------------------------------------------
__global__ void prep_kernel(int* __restrict__ counts, float* __restrict__ norms,
                            int n) {
    int idx = blockIdx.x * 256 + threadIdx.x;
    if (idx < n) counts[idx] = 0;
    if (idx < 3) norms[idx] = 0.f;
}

__global__ void hist_kernel(const int* __restrict__ rs, int* __restrict__ counts,
                            int B) {
    int b = blockIdx.x * 256 + threadIdx.x;
    if (b < B) atomicAdd(&counts[rs[b]], 1);
}

__global__ __launch_bounds__(1024)
void scan_kernel(const int* __restrict__ counts, int* __restrict__ offs,
                 int* __restrict__ cursor, int n) {
    __shared__ int buf[2][1024];
    const int t = threadIdx.x;
    int cur = 0;
    buf[0][t] = (t < n) ? counts[t] : 0;
    __syncthreads();
    for (int d = 1; d < 1024; d <<= 1) {
        int x = buf[cur][t] + ((t >= d) ? buf[cur][t - d] : 0);
        buf[cur ^ 1][t] = x;
        cur ^= 1;
        __syncthreads();
    }
    if (t < n) {
        int inc = buf[cur][t];
        offs[t + 1] = inc;
        cursor[t] = inc - counts[t];
        if (t == 0) offs[0] = 0;
    }
}

__global__ void fill_kernel(const int* __restrict__ rs, int* __restrict__ cursor,
                            int* __restrict__ list, int B) {
    int b = blockIdx.x * 256 + threadIdx.x;
    if (b < B) {
        int pos = atomicAdd(&cursor[rs[b]], 1);
        list[pos] = b;
    }
}

// ---------------- Stage 2: bucketed bilinear forms, i-chunked ---------------
__global__ __launch_bounds__(256)
void stage2_kernel(const int* __restrict__ list, const int* __restrict__ offs,
                   const int* __restrict__ ps, const int* __restrict__ qs,
                   const float* __restrict__ P, const float* __restrict__ Q,
                   const unsigned short* __restrict__ WR,
                   float* __restrict__ partial, int r_lo, int B) {
    const int r_rel = blockIdx.x;
    const int r     = r_lo + r_rel;
    const int start = offs[r], end = offs[r + 1];
    if (start >= end) return;
    const int ic     = blockIdx.y;
    const int i0base = ic * 64;
    const int t = threadIdx.x;
    const int g = t >> 6;   // wave id
    const int c = t & 63;   // k-group (4 elems)

    __shared__ float Lp[8][68];
    __shared__ float Lq[8][DDIM];
    __shared__ float red[8][4];

    const unsigned short* M = WR + (size_t)r_rel * NIK;

    for (int s0 = start; s0 < end; s0 += 8) {
        const int ns = min(8, end - s0);
        for (int x = t; x < ns * 64; x += 256) {
            int s = x >> 6, d = x & 63;
            Lp[s][d] = P[(size_t)ps[list[s0 + s]] * DDIM + i0base + d];
        }
        for (int x = t; x < ns * DDIM; x += 256) {
            int s = x >> 8, d = x & 255;
            Lq[s][d] = Q[(size_t)qs[list[s0 + s]] * DDIM + d];
        }
        __syncthreads();

        float qq[8][4];
        float acc[8];
#pragma unroll
        for (int s = 0; s < 8; ++s) {
            acc[s] = 0.f;
            qq[s][0] = Lq[s][c * 4 + 0];
            qq[s][1] = Lq[s][c * 4 + 1];
            qq[s][2] = Lq[s][c * 4 + 2];
            qq[s][3] = Lq[s][c * 4 + 3];
        }

#pragma unroll
        for (int ii = 0; ii < 16; ++ii) {
            const int irow = g * 16 + ii;
            uint2 v = *reinterpret_cast<const uint2*>(
                M + (size_t)(i0base + irow) * DDIM + c * 4);
            const unsigned short* h = reinterpret_cast<const unsigned short*>(&v);
            float m0 = bf2f(h[0]), m1 = bf2f(h[1]);
            float m2 = bf2f(h[2]), m3 = bf2f(h[3]);
#pragma unroll
            for (int s = 0; s < 8; ++s) {
                float pv = Lp[s][irow];
                acc[s] += pv * (m0 * qq[s][0] + m1 * qq[s][1] +
                                m2 * qq[s][2] + m3 * qq[s][3]);
            }
        }

#pragma unroll
        for (int s = 0; s < 8; ++s) {
            float a = acc[s];
#pragma unroll
            for (int off = 32; off; off >>= 1) a += __shfl_down(a, off, 64);
            if (c == 0) red[s][g] = a;
        }
        __syncthreads();
        if (t < ns) {
            int b = list[s0 + t];
            partial[(size_t)ic * B + b] =
                red[t][0] + red[t][1] + red[t][2] + red[t][3];
        }
        __syncthreads();
    }
}

__global__ void sum_out_kernel(const float* __restrict__ partial,
                               float* __restrict__ out, int B) {
    int b = blockIdx.x * 256 + threadIdx.x;
    if (b < B)
        out[b] = (partial[b] + partial[(size_t)B + b]) +
                 (partial[(size_t)2 * B + b] + partial[(size_t)3 * B + b]);
}

// ---------------- Norms -----------------------------------------------------
__global__ __launch_bounds__(256)
void norm_kernel(const int* __restrict__ ps, const int* __restrict__ qs,
                 const int* __restrict__ rs, const float* __restrict__ P,
                 const float* __restrict__ Q, const float* __restrict__ R,
                 float* __restrict__ accum, int B) {
    const int which = blockIdx.y;
    const int*   idx = (which == 0) ? ps : (which == 1) ? qs : rs;
    const float* tab = (which == 0) ? P : (which == 1) ? Q : R;
    float a = 0.f;
    const int total = B * 64;
    for (int e = blockIdx.x * 256 + threadIdx.x; e < total; e += gridDim.x * 256) {
        int b = e >> 6, cc = e & 63;
        float4 v = *reinterpret_cast<const float4*>(tab + (size_t)idx[b] * DDIM + cc * 4);
        a += v.x * v.x + v.y * v.y + v.z * v.z + v.w * v.w;
    }
#pragma unroll
    for (int off = 32; off; off >>= 1) a += __shfl_down(a, off, 64);
    __shared__ float red[4];
    if ((threadIdx.x & 63) == 0) red[threadIdx.x >> 6] = a;
    __syncthreads();
    if (threadIdx.x == 0) atomicAdd(accum + which, red[0] + red[1] + red[2] + red[3]);
}

__global__ void finalize_kernel(const float* __restrict__ n,
                                float* __restrict__ out, int nB) {
    if (threadIdx.x == 0 && blockIdx.x == 0)
        out[nB] = 0.01f * (sqrtf(n[0]) + sqrtf(n[1]) + sqrtf(n[2]));
}

// ---------------- Launch -----------------------------------------------------
extern "C" void kernel_launch(void* const* d_in, const int* in_sizes, int n_in,
                              void* d_out, int out_size, void* d_ws,
                              size_t ws_size, hipStream_t stream) {
    const int*   ps = (const int*)d_in[0];
    const int*   qs = (const int*)d_in[1];
    const int*   rs = (const int*)d_in[2];
    const float* P  = (const float*)d_in[3];
    const float* Q  = (const float*)d_in[4];
    const float* R  = (const float*)d_in[5];
    const float* W  = (const float*)d_in[6];
    float* out = (float*)d_out;

    const int B      = in_sizes[0];
    const int NUM_RS = in_sizes[5] / DDIM;

    // ws layout
    size_t off = 0;
    float* norms = (float*)((char*)d_ws + off);          off += 256;
    int* counts  = (int*)((char*)d_ws + off);            off += (size_t)NUM_RS * 4;
    int* offs    = (int*)((char*)d_ws + off);            off += (size_t)(NUM_RS + 1) * 4;
    int* cursor  = (int*)((char*)d_ws + off);            off += (size_t)NUM_RS * 4;
    int* list    = (int*)((char*)d_ws + off);            off += (size_t)B * 4;
    off = (off + 255) & ~(size_t)255;
    float* partial = (float*)((char*)d_ws + off);        off += (size_t)NCH * B * 4;
    off = (off + 255) & ~(size_t)255;
    unsigned short* Rb = (unsigned short*)((char*)d_ws + off);
    off += (size_t)NUM_RS * DDIM * 2;
    off = (off + 255) & ~(size_t)255;
    unsigned short* Wt = (unsigned short*)((char*)d_ws + off);
    off += (size_t)NIK * DDIM * 2;
    off = (off + 255) & ~(size_t)255;
    unsigned short* WR = (unsigned short*)((char*)d_ws + off);

    size_t wr_bytes = (ws_size > off) ? ws_size - off : 0;
    int max_chunk = (int)(wr_bytes / ((size_t)NIK * 2));
    if (max_chunk > NUM_RS) max_chunk = NUM_RS;
    if (max_chunk < 1) max_chunk = 1;

    // CSR + norms
    prep_kernel<<<(NUM_RS + 255) / 256, 256, 0, stream>>>(counts, norms, NUM_RS);
    hist_kernel<<<(B + 255) / 256, 256, 0, stream>>>(rs, counts, B);
    scan_kernel<<<1, 1024, 0, stream>>>(counts, offs, cursor, NUM_RS);
    fill_kernel<<<(B + 255) / 256, 256, 0, stream>>>(rs, cursor, list, B);
    norm_kernel<<<dim3(128, 3), 256, 0, stream>>>(ps, qs, rs, P, Q, R, norms, B);
    finalize_kernel<<<1, 64, 0, stream>>>(norms, out, B);

    // conversions
    conv_r_kernel<<<(NUM_RS * DDIM / 4 + 255) / 256, 256, 0, stream>>>(
        R, Rb, NUM_RS * DDIM / 4);
    conv_wt_kernel<<<dim3(4, 2, DDIM), 256, 0, stream>>>(W, Wt);

    for (int lo = 0; lo < NUM_RS; lo += max_chunk) {
        int cnt = NUM_RS - lo;
        if (cnt > max_chunk) cnt = max_chunk;
        dim3 g1((cnt + BM - 1) / BM, NIK / BN);
        stage1_kernel<<<g1, 256, 0, stream>>>(Rb, Wt, WR, lo, cnt);
        stage2_kernel<<<dim3(cnt, NCH), 256, 0, stream>>>(
            list, offs, ps, qs, P, Q, WR, partial, lo, B);
    }
    sum_out_kernel<<<(B + 255) / 256, 256, 0, stream>>>(partial, out, B);
}

// Round 4
// 182.440 us; speedup vs baseline: 3.0501x; 1.0575x over previous
//
#include <hip/hip_runtime.h>
#include <hip/hip_bf16.h>

// TuckER: out[b] = sum_{i,j,k} p[b,i] r[b,j] q[b,k] W[i,j,k]
// Pipeline:
//   conv_r:   R fp32 -> bf16
//   conv_wt:  W[i][j][k] fp32 -> Wt[(i,k)][j] bf16 (transpose)
//   stage1:   WR[r,(i,k)] = sum_j R[r,j] Wt[(i,k),j]   MFMA bf16 GEMM
//             2-phase double-buffered; WR stored ik-PERMUTED for 64B-sector
//             aligned stores (permutation: m = h*32+g*8+f'*4+v within each
//             64-ik chunk, where ik_local = (2h+f')*16 + g*4 + v)
//   CSR:      bucket samples by r
//   stage2:   partial[ic,b] = p^T WR[rs_b] q (Lq fill applies the permutation)
//   sum_out, norms

#define DDIM 256
#define NIK  65536
#define BM   128
#define BN   128
#define BK   64
#define NCH  4

typedef unsigned int uint;
typedef __attribute__((ext_vector_type(8))) short bf16x8;
typedef __attribute__((ext_vector_type(4))) float f32x4;

static __device__ __forceinline__ unsigned short f2bf(float f) {
    __hip_bfloat16 h = __float2bfloat16(f);
    return *reinterpret_cast<unsigned short*>(&h);
}
static __device__ __forceinline__ float bf2f(unsigned short u) {
    return __uint_as_float(((uint)u) << 16);
}

#define GLOAD_LDS16(gsrc, ldst)                                                \
    __builtin_amdgcn_global_load_lds(                                          \
        (const __attribute__((address_space(1))) void*)(gsrc),                 \
        (__attribute__((address_space(3))) void*)(ldst), 16, 0, 0)

// ---------------- convert R to bf16 -----------------------------------------
__global__ __launch_bounds__(256)
void conv_r_kernel(const float* __restrict__ R, unsigned short* __restrict__ Rb,
                   int n4) {
    int idx = blockIdx.x * 256 + threadIdx.x;
    if (idx < n4) {
        float4 v = *reinterpret_cast<const float4*>(R + idx * 4);
        ushort4 o;
        o.x = f2bf(v.x); o.y = f2bf(v.y); o.z = f2bf(v.z); o.w = f2bf(v.w);
        *reinterpret_cast<ushort4*>(Rb + idx * 4) = o;
    }
}

// ---------------- transpose-convert W: [i][j][k] f32 -> [(i,k)][j] bf16 -----
__global__ __launch_bounds__(256)
void conv_wt_kernel(const float* __restrict__ W, unsigned short* __restrict__ Wt) {
    const int k0 = blockIdx.x * 64;
    const int j0 = blockIdx.y * 128;
    const int i  = blockIdx.z;
    const int t  = threadIdx.x;

    __shared__ float sT[64][129];

    const float* Wi = W + (size_t)i * NIK;
#pragma unroll
    for (int it = 0; it < 8; ++it) {
        int slot = it * 256 + t;
        int jj = slot >> 4, c = slot & 15;
        float4 v = *reinterpret_cast<const float4*>(
            Wi + (size_t)(j0 + jj) * DDIM + k0 + c * 4);
        sT[c * 4 + 0][jj] = v.x;
        sT[c * 4 + 1][jj] = v.y;
        sT[c * 4 + 2][jj] = v.z;
        sT[c * 4 + 3][jj] = v.w;
    }
    __syncthreads();
#pragma unroll
    for (int it = 0; it < 4; ++it) {
        int u = it * 256 + t;
        int kk = u >> 4, jg = u & 15;
        union { unsigned short us[8]; uint4 v; } pk;
#pragma unroll
        for (int m = 0; m < 8; ++m) pk.us[m] = f2bf(sT[kk][jg * 8 + m]);
        *reinterpret_cast<uint4*>(
            Wt + (size_t)(i * DDIM + k0 + kk) * DDIM + j0 + jg * 8) = pk.v;
    }
}

// ---------------- Stage 1: MFMA GEMM, 2-phase double-buffered ---------------
__global__ __launch_bounds__(256, 2)
void stage1_kernel(const unsigned short* __restrict__ Rb,
                   const unsigned short* __restrict__ Wt,
                   unsigned short* __restrict__ WR,
                   int r_lo, int cnt) {
    const int t    = threadIdx.x;
    const int lane = t & 63;
    const int wid  = t >> 6;
    const int r0   = blockIdx.x * BM;   // r fastest: 8 r-blocks share Wt panel
    const int n0   = blockIdx.y * BN;

    __shared__ char smem[65536];
    char* Abuf[2] = {smem, smem + 16384};
    char* Bbuf[2] = {smem + 32768, smem + 49152};

    const int wr = (wid >> 1) * 64;
    const int wn = (wid & 1) * 64;

    f32x4 acc[4][4];
#pragma unroll
    for (int a = 0; a < 4; ++a)
#pragma unroll
        for (int b = 0; b < 4; ++b) {
            acc[a][b][0] = 0.f; acc[a][b][1] = 0.f;
            acc[a][b][2] = 0.f; acc[a][b][3] = 0.f;
        }

    // staging addresses (constant across kt except j0)
    const int srow = t >> 3;          // 0..31 base rows (x4 chunks of rows)
    const int sg   = t & 7;           // 16B granule within 128B row
    int arow_g = r0 + srow;           // A rows handled in 4 chunks of 32
    // clamp per chunk below

#define STAGE_KT(kt, Ab, Bb)                                                    \
    {                                                                           \
        const int j0s = (kt) * BK;                                              \
        _Pragma("unroll")                                                       \
        for (int c = 0; c < 4; ++c) {                                           \
            int u = c * 256 + t;                                                \
            int row = u >> 3, g = u & 7;                                        \
            int rg = r0 + row;                                                  \
            if (rg >= cnt) rg = 0;                                              \
            const unsigned short* src =                                         \
                Rb + (size_t)(r_lo + rg) * DDIM + j0s + ((g ^ (row & 7)) << 3); \
            GLOAD_LDS16(src, (Ab) + u * 16);                                    \
        }                                                                       \
        _Pragma("unroll")                                                       \
        for (int c = 0; c < 4; ++c) {                                           \
            int u = c * 256 + t;                                                \
            int row = u >> 3, g = u & 7;                                        \
            const unsigned short* src =                                         \
                Wt + (size_t)(n0 + row) * DDIM + j0s + ((g ^ (row & 7)) << 3);  \
            GLOAD_LDS16(src, (Bb) + u * 16);                                    \
        }                                                                       \
    }

    STAGE_KT(0, Abuf[0], Bbuf[0]);
    __syncthreads();  // drain prologue

#pragma unroll
    for (int kt = 0; kt < 4; ++kt) {
        const int cur = kt & 1;
        if (kt < 3) STAGE_KT(kt + 1, Abuf[cur ^ 1], Bbuf[cur ^ 1]);

#pragma unroll
        for (int ks = 0; ks < 2; ++ks) {
            bf16x8 a[4], b[4];
            const int jg = ks * 4 + (lane >> 4);
#pragma unroll
            for (int f = 0; f < 4; ++f) {
                int rowB = wn + f * 16 + (lane & 15);
                a[f] = *reinterpret_cast<const bf16x8*>(
                    Bbuf[cur] + rowB * 128 + ((jg ^ (rowB & 7)) << 4));
                int rowA = wr + f * 16 + (lane & 15);
                b[f] = *reinterpret_cast<const bf16x8*>(
                    Abuf[cur] + rowA * 128 + ((jg ^ (rowA & 7)) << 4));
            }
#pragma unroll
            for (int fi = 0; fi < 4; ++fi)
#pragma unroll
                for (int fr = 0; fr < 4; ++fr)
                    acc[fi][fr] = __builtin_amdgcn_mfma_f32_16x16x32_bf16(
                        a[fi], b[fr], acc[fi][fr], 0, 0, 0);
        }
        __syncthreads();  // drains next-tile loads (flew under MFMA)
    }

    // epilogue: permuted-contiguous stores.
    // lane owns ik_local = fi*16 + g*4 + v (g = lane>>4); stored at
    // m = h*32 + g*8 + f'*4 + v  (fi = 2h+f') -> 32B/lane contiguous,
    // 4 lanes per r cover 64B aligned.
    const int rsel = lane & 15;
    const int g    = lane >> 4;
#pragma unroll
    for (int fr = 0; fr < 4; ++fr) {
        int r = r0 + wr + fr * 16 + rsel;
        if (r < cnt) {
#pragma unroll
            for (int h = 0; h < 2; ++h) {
                union { unsigned short us[8]; uint4 v; } pk;
#pragma unroll
                for (int v = 0; v < 4; ++v) {
                    pk.us[v]     = f2bf(acc[2 * h][fr][v]);
                    pk.us[4 + v] = f2bf(acc[2 * h + 1][fr][v]);
                }
                *reinterpret_cast<uint4*>(
                    WR + (size_t)r * NIK + n0 + wn + h * 32 + g * 8) = pk.v;
            }
        }
    }
#undef STAGE_KT
}

// ---------------- CSR bucketing ---------------------------------------------
__global__ void prep_kernel(int* __restrict__ counts, float* __restrict__ norms,
                            int n) {
    int idx = blockIdx.x * 256 + threadIdx.x;
    if (idx < n) counts[idx] = 0;
    if (idx < 3) norms[idx] = 0.f;
}

__global__ void hist_kernel(const int* __restrict__ rs, int* __restrict__ counts,
                            int B) {
    int b = blockIdx.x * 256 + threadIdx.x;
    if (b < B) atomicAdd(&counts[rs[b]], 1);
}

__global__ __launch_bounds__(1024)
void scan_kernel(const int* __restrict__ counts, int* __restrict__ offs,
                 int* __restrict__ cursor, int n) {
    __shared__ int buf[2][1024];
    const int t = threadIdx.x;
    int cur = 0;
    buf[0][t] = (t < n) ? counts[t] : 0;
    __syncthreads();
    for (int d = 1; d < 1024; d <<= 1) {
        int x = buf[cur][t] + ((t >= d) ? buf[cur][t - d] : 0);
        buf[cur ^ 1][t] = x;
        cur ^= 1;
        __syncthreads();
    }
    if (t < n) {
        int inc = buf[cur][t];
        offs[t + 1] = inc;
        cursor[t] = inc - counts[t];
        if (t == 0) offs[0] = 0;
    }
}

__global__ void fill_kernel(const int* __restrict__ rs, int* __restrict__ cursor,
                            int* __restrict__ list, int B) {
    int b = blockIdx.x * 256 + threadIdx.x;
    if (b < B) {
        int pos = atomicAdd(&cursor[rs[b]], 1);
        list[pos] = b;
    }
}

// ---------------- Stage 2: bucketed bilinear forms, i-chunked ---------------
__global__ __launch_bounds__(256)
void stage2_kernel(const int* __restrict__ list, const int* __restrict__ offs,
                   const int* __restrict__ ps, const int* __restrict__ qs,
                   const float* __restrict__ P, const float* __restrict__ Q,
                   const unsigned short* __restrict__ WR,
                   float* __restrict__ partial, int r_lo, int B) {
    const int r_rel = blockIdx.x;
    const int r     = r_lo + r_rel;
    const int start = offs[r], end = offs[r + 1];
    if (start >= end) return;
    const int ic     = blockIdx.y;
    const int i0base = ic * 64;
    const int t = threadIdx.x;
    const int g = t >> 6;
    const int c = t & 63;

    __shared__ float Lp[8][68];
    __shared__ float Lq[8][DDIM];
    __shared__ float red[8][4];

    const unsigned short* M = WR + (size_t)r_rel * NIK;

    for (int s0 = start; s0 < end; s0 += 8) {
        const int ns = min(8, end - s0);
        for (int x = t; x < ns * 64; x += 256) {
            int s = x >> 6, d = x & 63;
            Lp[s][d] = P[(size_t)ps[list[s0 + s]] * DDIM + i0base + d];
        }
        for (int x = t; x < ns * DDIM; x += 256) {
            int s = x >> 8, d = x & 255;
            // apply stage1's ik permutation: within each 64-k chunk,
            // lo = fi*16+gg*4+v  ->  m = (fi>>1)*32 + gg*8 + (fi&1)*4 + v
            int lo = d & 63;
            int fi = lo >> 4, gg = (lo >> 2) & 3, v = lo & 3;
            int m  = (d & 192) | ((fi >> 1) * 32 + gg * 8 + (fi & 1) * 4 + v);
            Lq[s][m] = Q[(size_t)qs[list[s0 + s]] * DDIM + d];
        }
        __syncthreads();

        float qq[8][4];
        float acc[8];
#pragma unroll
        for (int s = 0; s < 8; ++s) {
            acc[s] = 0.f;
            qq[s][0] = Lq[s][c * 4 + 0];
            qq[s][1] = Lq[s][c * 4 + 1];
            qq[s][2] = Lq[s][c * 4 + 2];
            qq[s][3] = Lq[s][c * 4 + 3];
        }

#pragma unroll
        for (int ii = 0; ii < 16; ++ii) {
            const int irow = g * 16 + ii;
            uint2 v = *reinterpret_cast<const uint2*>(
                M + (size_t)(i0base + irow) * DDIM + c * 4);
            const unsigned short* h = reinterpret_cast<const unsigned short*>(&v);
            float m0 = bf2f(h[0]), m1 = bf2f(h[1]);
            float m2 = bf2f(h[2]), m3 = bf2f(h[3]);
#pragma unroll
            for (int s = 0; s < 8; ++s) {
                float pv = Lp[s][irow];
                acc[s] += pv * (m0 * qq[s][0] + m1 * qq[s][1] +
                                m2 * qq[s][2] + m3 * qq[s][3]);
            }
        }

#pragma unroll
        for (int s = 0; s < 8; ++s) {
            float a = acc[s];
#pragma unroll
            for (int off = 32; off; off >>= 1) a += __shfl_down(a, off, 64);
            if (c == 0) red[s][g] = a;
        }
        __syncthreads();
        if (t < ns) {
            int b = list[s0 + t];
            partial[(size_t)ic * B + b] =
                red[t][0] + red[t][1] + red[t][2] + red[t][3];
        }
        __syncthreads();
    }
}

__global__ void sum_out_kernel(const float* __restrict__ partial,
                               float* __restrict__ out, int B) {
    int b = blockIdx.x * 256 + threadIdx.x;
    if (b < B)
        out[b] = (partial[b] + partial[(size_t)B + b]) +
                 (partial[(size_t)2 * B + b] + partial[(size_t)3 * B + b]);
}

// ---------------- Norms -----------------------------------------------------
__global__ __launch_bounds__(256)
void norm_kernel(const int* __restrict__ ps, const int* __restrict__ qs,
                 const int* __restrict__ rs, const float* __restrict__ P,
                 const float* __restrict__ Q, const float* __restrict__ R,
                 float* __restrict__ accum, int B) {
    const int which = blockIdx.y;
    const int*   idx = (which == 0) ? ps : (which == 1) ? qs : rs;
    const float* tab = (which == 0) ? P : (which == 1) ? Q : R;
    float a = 0.f;
    const int total = B * 64;
    for (int e = blockIdx.x * 256 + threadIdx.x; e < total; e += gridDim.x * 256) {
        int b = e >> 6, cc = e & 63;
        float4 v = *reinterpret_cast<const float4*>(tab + (size_t)idx[b] * DDIM + cc * 4);
        a += v.x * v.x + v.y * v.y + v.z * v.z + v.w * v.w;
    }
#pragma unroll
    for (int off = 32; off; off >>= 1) a += __shfl_down(a, off, 64);
    __shared__ float red[4];
    if ((threadIdx.x & 63) == 0) red[threadIdx.x >> 6] = a;
    __syncthreads();
    if (threadIdx.x == 0) atomicAdd(accum + which, red[0] + red[1] + red[2] + red[3]);
}

__global__ void finalize_kernel(const float* __restrict__ n,
                                float* __restrict__ out, int nB) {
    if (threadIdx.x == 0 && blockIdx.x == 0)
        out[nB] = 0.01f * (sqrtf(n[0]) + sqrtf(n[1]) + sqrtf(n[2]));
}

// ---------------- Launch -----------------------------------------------------
extern "C" void kernel_launch(void* const* d_in, const int* in_sizes, int n_in,
                              void* d_out, int out_size, void* d_ws,
                              size_t ws_size, hipStream_t stream) {
    const int*   ps = (const int*)d_in[0];
    const int*   qs = (const int*)d_in[1];
    const int*   rs = (const int*)d_in[2];
    const float* P  = (const float*)d_in[3];
    const float* Q  = (const float*)d_in[4];
    const float* R  = (const float*)d_in[5];
    const float* W  = (const float*)d_in[6];
    float* out = (float*)d_out;

    const int B      = in_sizes[0];
    const int NUM_RS = in_sizes[5] / DDIM;

    size_t off = 0;
    float* norms = (float*)((char*)d_ws + off);          off += 256;
    int* counts  = (int*)((char*)d_ws + off);            off += (size_t)NUM_RS * 4;
    int* offs    = (int*)((char*)d_ws + off);            off += (size_t)(NUM_RS + 1) * 4;
    int* cursor  = (int*)((char*)d_ws + off);            off += (size_t)NUM_RS * 4;
    int* list    = (int*)((char*)d_ws + off);            off += (size_t)B * 4;
    off = (off + 255) & ~(size_t)255;
    float* partial = (float*)((char*)d_ws + off);        off += (size_t)NCH * B * 4;
    off = (off + 255) & ~(size_t)255;
    unsigned short* Rb = (unsigned short*)((char*)d_ws + off);
    off += (size_t)NUM_RS * DDIM * 2;
    off = (off + 255) & ~(size_t)255;
    unsigned short* Wt = (unsigned short*)((char*)d_ws + off);
    off += (size_t)NIK * DDIM * 2;
    off = (off + 255) & ~(size_t)255;
    unsigned short* WR = (unsigned short*)((char*)d_ws + off);

    size_t wr_bytes = (ws_size > off) ? ws_size - off : 0;
    int max_chunk = (int)(wr_bytes / ((size_t)NIK * 2));
    if (max_chunk > NUM_RS) max_chunk = NUM_RS;
    if (max_chunk < 1) max_chunk = 1;

    prep_kernel<<<(NUM_RS + 255) / 256, 256, 0, stream>>>(counts, norms, NUM_RS);
    hist_kernel<<<(B + 255) / 256, 256, 0, stream>>>(rs, counts, B);
    scan_kernel<<<1, 1024, 0, stream>>>(counts, offs, cursor, NUM_RS);
    fill_kernel<<<(B + 255) / 256, 256, 0, stream>>>(rs, cursor, list, B);
    norm_kernel<<<dim3(128, 3), 256, 0, stream>>>(ps, qs, rs, P, Q, R, norms, B);
    finalize_kernel<<<1, 64, 0, stream>>>(norms, out, B);

    conv_r_kernel<<<(NUM_RS * DDIM / 4 + 255) / 256, 256, 0, stream>>>(
        R, Rb, NUM_RS * DDIM / 4);
    conv_wt_kernel<<<dim3(4, 2, DDIM), 256, 0, stream>>>(W, Wt);

    for (int lo = 0; lo < NUM_RS; lo += max_chunk) {
        int cnt = NUM_RS - lo;
        if (cnt > max_chunk) cnt = max_chunk;
        dim3 g1((cnt + BM - 1) / BM, NIK / BN);
        stage1_kernel<<<g1, 256, 0, stream>>>(Rb, Wt, WR, lo, cnt);
        stage2_kernel<<<dim3(cnt, NCH), 256, 0, stream>>>(
            list, offs, ps, qs, P, Q, WR, partial, lo, B);
    }
    sum_out_kernel<<<(B + 255) / 256, 256, 0, stream>>>(partial, out, B);
}

// Round 5
// 148.298 us; speedup vs baseline: 3.7523x; 1.2302x over previous
//
#include <hip/hip_runtime.h>
#include <hip/hip_bf16.h>

// TuckER: out[b] = sum_{i,j,k} p[b,i] r[b,j] q[b,k] W[i,j,k]
// Pipeline:
//   conv_r:   R fp32 -> bf16
//   conv_wt:  W[i][j][k] fp32 -> Wt[(i,k)][j] bf16 (transpose)
//   stage1:   WR[r,(i,k)] = sum_j R[r,j] Wt[(ik),j]  MFMA bf16 GEMM,
//             output written in MFMA-A-fragment TILED layout:
//             elem(r,i,k) at r*65536 + (k>>5)*8192 + (i>>4)*512
//                          + (i&15)*32 + kg*8 + e
//             where k&31 = (e>>2)*16 + kg*4 + (e&3)   (lane granule = 16B)
//   CSR:      bucket samples by r
//   stage2:   per-bucket MFMA: A = WR frags (streamed), B = q (16 samples),
//             D[i][sample] dotted with p -> partial[ihalf][b]
//   sum_out, norms

#define DDIM 256
#define NIK  65536
#define BM   128
#define BN   128
#define BK   64
#define NCH2 2

typedef unsigned int uint;
typedef __attribute__((ext_vector_type(8))) short bf16x8;
typedef __attribute__((ext_vector_type(4))) float f32x4;

static __device__ __forceinline__ unsigned short f2bf(float f) {
    __hip_bfloat16 h = __float2bfloat16(f);
    return *reinterpret_cast<unsigned short*>(&h);
}
static __device__ __forceinline__ float bf2f(unsigned short u) {
    return __uint_as_float(((uint)u) << 16);
}

#define GLOAD_LDS16(gsrc, ldst)                                                \
    __builtin_amdgcn_global_load_lds(                                          \
        (const __attribute__((address_space(1))) void*)(gsrc),                 \
        (__attribute__((address_space(3))) void*)(ldst), 16, 0, 0)

// ---------------- convert R to bf16 -----------------------------------------
__global__ __launch_bounds__(256)
void conv_r_kernel(const float* __restrict__ R, unsigned short* __restrict__ Rb,
                   int n4) {
    int idx = blockIdx.x * 256 + threadIdx.x;
    if (idx < n4) {
        float4 v = *reinterpret_cast<const float4*>(R + idx * 4);
        ushort4 o;
        o.x = f2bf(v.x); o.y = f2bf(v.y); o.z = f2bf(v.z); o.w = f2bf(v.w);
        *reinterpret_cast<ushort4*>(Rb + idx * 4) = o;
    }
}

// ---------------- transpose-convert W: [i][j][k] f32 -> [(i,k)][j] bf16 -----
__global__ __launch_bounds__(256)
void conv_wt_kernel(const float* __restrict__ W, unsigned short* __restrict__ Wt) {
    const int k0 = blockIdx.x * 64;
    const int j0 = blockIdx.y * 128;
    const int i  = blockIdx.z;
    const int t  = threadIdx.x;

    __shared__ float sT[64][129];

    const float* Wi = W + (size_t)i * NIK;
#pragma unroll
    for (int it = 0; it < 8; ++it) {
        int slot = it * 256 + t;
        int jj = slot >> 4, c = slot & 15;
        float4 v = *reinterpret_cast<const float4*>(
            Wi + (size_t)(j0 + jj) * DDIM + k0 + c * 4);
        sT[c * 4 + 0][jj] = v.x;
        sT[c * 4 + 1][jj] = v.y;
        sT[c * 4 + 2][jj] = v.z;
        sT[c * 4 + 3][jj] = v.w;
    }
    __syncthreads();
#pragma unroll
    for (int it = 0; it < 4; ++it) {
        int u = it * 256 + t;
        int kk = u >> 4, jg = u & 15;
        union { unsigned short us[8]; uint4 v; } pk;
#pragma unroll
        for (int m = 0; m < 8; ++m) pk.us[m] = f2bf(sT[kk][jg * 8 + m]);
        *reinterpret_cast<uint4*>(
            Wt + (size_t)(i * DDIM + k0 + kk) * DDIM + j0 + jg * 8) = pk.v;
    }
}

// ---------------- Stage 1: MFMA GEMM, 2-phase double-buffered ---------------
__global__ __launch_bounds__(256, 2)
void stage1_kernel(const unsigned short* __restrict__ Rb,
                   const unsigned short* __restrict__ Wt,
                   unsigned short* __restrict__ WR,
                   int r_lo, int cnt) {
    const int t    = threadIdx.x;
    const int lane = t & 63;
    const int wid  = t >> 6;
    const int r0   = blockIdx.x * BM;
    const int n0   = blockIdx.y * BN;

    __shared__ char smem[65536];
    char* Abuf[2] = {smem, smem + 16384};
    char* Bbuf[2] = {smem + 32768, smem + 49152};

    const int wr = (wid >> 1) * 64;
    const int wn = (wid & 1) * 64;

    f32x4 acc[4][4];
#pragma unroll
    for (int a = 0; a < 4; ++a)
#pragma unroll
        for (int b = 0; b < 4; ++b) {
            acc[a][b][0] = 0.f; acc[a][b][1] = 0.f;
            acc[a][b][2] = 0.f; acc[a][b][3] = 0.f;
        }

#define STAGE_KT(kt, Ab, Bb)                                                    \
    {                                                                           \
        const int j0s = (kt) * BK;                                              \
        _Pragma("unroll")                                                       \
        for (int c = 0; c < 4; ++c) {                                           \
            int u = c * 256 + t;                                                \
            int row = u >> 3, g = u & 7;                                        \
            int rg = r0 + row;                                                  \
            if (rg >= cnt) rg = 0;                                              \
            const unsigned short* src =                                         \
                Rb + (size_t)(r_lo + rg) * DDIM + j0s + ((g ^ (row & 7)) << 3); \
            GLOAD_LDS16(src, (Ab) + u * 16);                                    \
        }                                                                       \
        _Pragma("unroll")                                                       \
        for (int c = 0; c < 4; ++c) {                                           \
            int u = c * 256 + t;                                                \
            int row = u >> 3, g = u & 7;                                        \
            const unsigned short* src =                                         \
                Wt + (size_t)(n0 + row) * DDIM + j0s + ((g ^ (row & 7)) << 3);  \
            GLOAD_LDS16(src, (Bb) + u * 16);                                    \
        }                                                                       \
    }

    STAGE_KT(0, Abuf[0], Bbuf[0]);
    __syncthreads();  // drain prologue

#pragma unroll
    for (int kt = 0; kt < 4; ++kt) {
        const int cur = kt & 1;
        if (kt < 3) STAGE_KT(kt + 1, Abuf[cur ^ 1], Bbuf[cur ^ 1]);

#pragma unroll
        for (int ks = 0; ks < 2; ++ks) {
            bf16x8 a[4], b[4];
            const int jg = ks * 4 + (lane >> 4);
#pragma unroll
            for (int f = 0; f < 4; ++f) {
                int rowB = wn + f * 16 + (lane & 15);
                a[f] = *reinterpret_cast<const bf16x8*>(
                    Bbuf[cur] + rowB * 128 + ((jg ^ (rowB & 7)) << 4));
                int rowA = wr + f * 16 + (lane & 15);
                b[f] = *reinterpret_cast<const bf16x8*>(
                    Abuf[cur] + rowA * 128 + ((jg ^ (rowA & 7)) << 4));
            }
#pragma unroll
            for (int fi = 0; fi < 4; ++fi)
#pragma unroll
                for (int fr = 0; fr < 4; ++fr)
                    acc[fi][fr] = __builtin_amdgcn_mfma_f32_16x16x32_bf16(
                        a[fi], b[fr], acc[fi][fr], 0, 0, 0);
        }
        __syncthreads();  // drains next-tile loads (flew under MFMA)
    }

    // epilogue: write MFMA-A-fragment tiled layout.
    // lane's elems (frag fi, reg vv): ik_local = wn + fi*16 + g*4 + vv,
    // g = lane>>4. i = n0>>8 fixed; k = (n0&255) + ik_local.
    // granule address (elems): r*65536 + kt*8192 + ib*512 + row16*32 + g*8,
    // granule e = (fi&1)*4 + vv.  Lanes {l,l+16,l+32,l+48}: same r, g=0..3
    // -> 64B contiguous per r-row per store inst.
    const int rsel   = lane & 15;
    const int g      = lane >> 4;
    const int i_g    = n0 >> 8;
    const int ibq    = i_g >> 4;
    const int row16  = i_g & 15;
    const int ktbase = ((n0 & 255) + wn) >> 5;
#pragma unroll
    for (int fr = 0; fr < 4; ++fr) {
        int r = r0 + wr + fr * 16 + rsel;
        if (r < cnt) {
            size_t rbase = (size_t)r * NIK + (size_t)ibq * 512 + row16 * 32 + g * 8;
#pragma unroll
            for (int ktsel = 0; ktsel < 2; ++ktsel) {
                union { unsigned short us[8]; uint4 v; } pk;
#pragma unroll
                for (int vv = 0; vv < 4; ++vv) {
                    pk.us[vv]     = f2bf(acc[2 * ktsel + 0][fr][vv]);
                    pk.us[4 + vv] = f2bf(acc[2 * ktsel + 1][fr][vv]);
                }
                *reinterpret_cast<uint4*>(
                    WR + rbase + (size_t)(ktbase + ktsel) * 8192) = pk.v;
            }
        }
    }
#undef STAGE_KT
}

// ---------------- CSR bucketing ---------------------------------------------
__global__ void prep_kernel(int* __restrict__ counts, float* __restrict__ norms,
                            int n) {
    int idx = blockIdx.x * 256 + threadIdx.x;
    if (idx < n) counts[idx] = 0;
    if (idx < 3) norms[idx] = 0.f;
}

__global__ void hist_kernel(const int* __restrict__ rs, int* __restrict__ counts,
                            int B) {
    int b = blockIdx.x * 256 + threadIdx.x;
    if (b < B) atomicAdd(&counts[rs[b]], 1);
}

__global__ __launch_bounds__(1024)
void scan_kernel(const int* __restrict__ counts, int* __restrict__ offs,
                 int* __restrict__ cursor, int n) {
    __shared__ int buf[2][1024];
    const int t = threadIdx.x;
    int cur = 0;
    buf[0][t] = (t < n) ? counts[t] : 0;
    __syncthreads();
    for (int d = 1; d < 1024; d <<= 1) {
        int x = buf[cur][t] + ((t >= d) ? buf[cur][t - d] : 0);
        buf[cur ^ 1][t] = x;
        cur ^= 1;
        __syncthreads();
    }
    if (t < n) {
        int inc = buf[cur][t];
        offs[t + 1] = inc;
        cursor[t] = inc - counts[t];
        if (t == 0) offs[0] = 0;
    }
}

__global__ void fill_kernel(const int* __restrict__ rs, int* __restrict__ cursor,
                            int* __restrict__ list, int B) {
    int b = blockIdx.x * 256 + threadIdx.x;
    if (b < B) {
        int pos = atomicAdd(&cursor[rs[b]], 1);
        list[pos] = b;
    }
}

// ---------------- Stage 2: per-bucket MFMA ----------------------------------
// A = WR tiled frags (row16 = lane&15 = i, kg = lane>>4), B = q of up to 16
// samples (col = lane&15 = sample). D[i][s] * p[s][i] -> partial.
__global__ __launch_bounds__(256)
void stage2_kernel(const int* __restrict__ list, const int* __restrict__ offs,
                   const int* __restrict__ ps, const int* __restrict__ qs,
                   const float* __restrict__ P, const float* __restrict__ Q,
                   const unsigned short* __restrict__ WR,
                   float* __restrict__ partial, int r_lo, int B) {
    const int r_rel = blockIdx.x;
    const int r     = r_lo + r_rel;
    const int start = offs[r], end = offs[r + 1];
    if (start >= end) return;
    const int ihalf = blockIdx.y;
    const int t     = threadIdx.x;
    const int lane  = t & 63;
    const int w     = t >> 6;
    const int s     = lane & 15;
    const int kg    = lane >> 4;

    __shared__ float Lq[16][258];
    __shared__ float Lp[16][133];
    __shared__ float red[16][4];

    const unsigned short* Mbase = WR + (size_t)r_rel * NIK;

    for (int s0 = start; s0 < end; s0 += 16) {
        const int ns = min(16, end - s0);
        for (int u = t; u < ns * 64; u += 256) {
            int ss = u >> 6, c = u & 63;
            *reinterpret_cast<float4*>(&Lq[ss][c * 4]) =
                *reinterpret_cast<const float4*>(
                    Q + (size_t)qs[list[s0 + ss]] * DDIM + c * 4);
        }
        for (int u = t; u < ns * 32; u += 256) {
            int ss = u >> 5, c = u & 31;
            *reinterpret_cast<float4*>(&Lp[ss][c * 4]) =
                *reinterpret_cast<const float4*>(
                    P + (size_t)ps[list[s0 + ss]] * DDIM + ihalf * 128 + c * 4);
        }
        __syncthreads();

        // B-frags: k = kt*32 + eh*16 + kg*4 + ev, granule e = eh*4+ev
        bf16x8 bq[8];
#pragma unroll
        for (int kt = 0; kt < 8; ++kt) {
#pragma unroll
            for (int eh = 0; eh < 2; ++eh) {
#pragma unroll
                for (int ev = 0; ev < 4; ++ev) {
                    float v = (s < ns) ? Lq[s][kt * 32 + eh * 16 + kg * 4 + ev]
                                       : 0.f;
                    bq[kt][eh * 4 + ev] = (short)f2bf(v);
                }
            }
        }

        float acc_out = 0.f;
#pragma unroll
        for (int ibl = 0; ibl < 2; ++ibl) {
            const int ibh = w * 2 + ibl;       // i-block within half (0..7)
            const int ibg = ihalf * 8 + ibh;   // global i-block
            const unsigned short* abase =
                Mbase + (size_t)ibg * 512 + (lane & 15) * 32 + kg * 8;
            bf16x8 af[8];
#pragma unroll
            for (int kt = 0; kt < 8; ++kt)
                af[kt] = *reinterpret_cast<const bf16x8*>(
                    abase + (size_t)kt * 8192);
            f32x4 acc = {0.f, 0.f, 0.f, 0.f};
#pragma unroll
            for (int kt = 0; kt < 8; ++kt)
                acc = __builtin_amdgcn_mfma_f32_16x16x32_bf16(af[kt], bq[kt],
                                                              acc, 0, 0, 0);
            // lane holds D rows (kg*4+reg) of block ibh, col = s
#pragma unroll
            for (int reg = 0; reg < 4; ++reg) {
                int il = ibh * 16 + kg * 4 + reg;
                float pv = (s < ns) ? Lp[s][il] : 0.f;
                acc_out += acc[reg] * pv;
            }
        }
        acc_out += __shfl_xor(acc_out, 16, 64);
        acc_out += __shfl_xor(acc_out, 32, 64);
        if (lane < 16) red[s][w] = acc_out;
        __syncthreads();
        if (t < ns)
            partial[(size_t)ihalf * B + list[s0 + t]] =
                red[t][0] + red[t][1] + red[t][2] + red[t][3];
        __syncthreads();
    }
}

__global__ void sum_out_kernel(const float* __restrict__ partial,
                               float* __restrict__ out, int B) {
    int b = blockIdx.x * 256 + threadIdx.x;
    if (b < B) out[b] = partial[b] + partial[(size_t)B + b];
}

// ---------------- Norms -----------------------------------------------------
__global__ __launch_bounds__(256)
void norm_kernel(const int* __restrict__ ps, const int* __restrict__ qs,
                 const int* __restrict__ rs, const float* __restrict__ P,
                 const float* __restrict__ Q, const float* __restrict__ R,
                 float* __restrict__ accum, int B) {
    const int which = blockIdx.y;
    const int*   idx = (which == 0) ? ps : (which == 1) ? qs : rs;
    const float* tab = (which == 0) ? P : (which == 1) ? Q : R;
    float a = 0.f;
    const int total = B * 64;
    for (int e = blockIdx.x * 256 + threadIdx.x; e < total; e += gridDim.x * 256) {
        int b = e >> 6, cc = e & 63;
        float4 v = *reinterpret_cast<const float4*>(tab + (size_t)idx[b] * DDIM + cc * 4);
        a += v.x * v.x + v.y * v.y + v.z * v.z + v.w * v.w;
    }
#pragma unroll
    for (int off = 32; off; off >>= 1) a += __shfl_down(a, off, 64);
    __shared__ float red[4];
    if ((threadIdx.x & 63) == 0) red[threadIdx.x >> 6] = a;
    __syncthreads();
    if (threadIdx.x == 0) atomicAdd(accum + which, red[0] + red[1] + red[2] + red[3]);
}

__global__ void finalize_kernel(const float* __restrict__ n,
                                float* __restrict__ out, int nB) {
    if (threadIdx.x == 0 && blockIdx.x == 0)
        out[nB] = 0.01f * (sqrtf(n[0]) + sqrtf(n[1]) + sqrtf(n[2]));
}

// ---------------- Launch -----------------------------------------------------
extern "C" void kernel_launch(void* const* d_in, const int* in_sizes, int n_in,
                              void* d_out, int out_size, void* d_ws,
                              size_t ws_size, hipStream_t stream) {
    const int*   ps = (const int*)d_in[0];
    const int*   qs = (const int*)d_in[1];
    const int*   rs = (const int*)d_in[2];
    const float* P  = (const float*)d_in[3];
    const float* Q  = (const float*)d_in[4];
    const float* R  = (const float*)d_in[5];
    const float* W  = (const float*)d_in[6];
    float* out = (float*)d_out;

    const int B      = in_sizes[0];
    const int NUM_RS = in_sizes[5] / DDIM;

    size_t off = 0;
    float* norms = (float*)((char*)d_ws + off);          off += 256;
    int* counts  = (int*)((char*)d_ws + off);            off += (size_t)NUM_RS * 4;
    int* offs    = (int*)((char*)d_ws + off);            off += (size_t)(NUM_RS + 1) * 4;
    int* cursor  = (int*)((char*)d_ws + off);            off += (size_t)NUM_RS * 4;
    int* list    = (int*)((char*)d_ws + off);            off += (size_t)B * 4;
    off = (off + 255) & ~(size_t)255;
    float* partial = (float*)((char*)d_ws + off);        off += (size_t)NCH2 * B * 4;
    off = (off + 255) & ~(size_t)255;
    unsigned short* Rb = (unsigned short*)((char*)d_ws + off);
    off += (size_t)NUM_RS * DDIM * 2;
    off = (off + 255) & ~(size_t)255;
    unsigned short* Wt = (unsigned short*)((char*)d_ws + off);
    off += (size_t)NIK * DDIM * 2;
    off = (off + 255) & ~(size_t)255;
    unsigned short* WR = (unsigned short*)((char*)d_ws + off);

    size_t wr_bytes = (ws_size > off) ? ws_size - off : 0;
    int max_chunk = (int)(wr_bytes / ((size_t)NIK * 2));
    if (max_chunk > NUM_RS) max_chunk = NUM_RS;
    if (max_chunk < 1) max_chunk = 1;

    prep_kernel<<<(NUM_RS + 255) / 256, 256, 0, stream>>>(counts, norms, NUM_RS);
    hist_kernel<<<(B + 255) / 256, 256, 0, stream>>>(rs, counts, B);
    scan_kernel<<<1, 1024, 0, stream>>>(counts, offs, cursor, NUM_RS);
    fill_kernel<<<(B + 255) / 256, 256, 0, stream>>>(rs, cursor, list, B);
    norm_kernel<<<dim3(128, 3), 256, 0, stream>>>(ps, qs, rs, P, Q, R, norms, B);
    finalize_kernel<<<1, 64, 0, stream>>>(norms, out, B);

    conv_r_kernel<<<(NUM_RS * DDIM / 4 + 255) / 256, 256, 0, stream>>>(
        R, Rb, NUM_RS * DDIM / 4);
    conv_wt_kernel<<<dim3(4, 2, DDIM), 256, 0, stream>>>(W, Wt);

    for (int lo = 0; lo < NUM_RS; lo += max_chunk) {
        int cnt = NUM_RS - lo;
        if (cnt > max_chunk) cnt = max_chunk;
        dim3 g1((cnt + BM - 1) / BM, NIK / BN);
        stage1_kernel<<<g1, 256, 0, stream>>>(Rb, Wt, WR, lo, cnt);
        stage2_kernel<<<dim3(cnt, NCH2), 256, 0, stream>>>(
            list, offs, ps, qs, P, Q, WR, partial, lo, B);
    }
    sum_out_kernel<<<(B + 255) / 256, 256, 0, stream>>>(partial, out, B);
}